// Round 14
// baseline (307.571 us; speedup 1.0000x reference)
//
#include <hip/hip_runtime.h>

#define NN 50000
#define DD 128
#define EE 800000
#define SLOTS 64          // max degree cap (Poisson(16): P(deg>=65) ~ 1e-20/node)
#define CSTRIDE 16        // ints per counter -> one counter per 64B line
#define NSHARD 8          // XCDs; blockIdx % 8 ~ XCD round-robin (perf heuristic only)
#define SHARD_NODES (NN / NSHARD)   // 6250

// merged prep+bucket block ranges (bucket first: it's the long pole)
#define BKT_BLKS  6256    // 782 chunks x 8 shards
#define CVT_BLKS  6250    // NN*DD/4 float4s / 256
#define WCAT_BLKS 384
#define ZR_BLKS   1

typedef short bf16x8 __attribute__((ext_vector_type(8)));   // 8 bf16 = 4 VGPRs
typedef float f32x4  __attribute__((ext_vector_type(4)));

// ---- bf16 helpers (RNE) ----
__device__ __forceinline__ unsigned short f2bf(float f) {
    union { float f; unsigned u; } c; c.f = f;
    unsigned r = c.u + 0x7fffu + ((c.u >> 16) & 1u);
    return (unsigned short)(r >> 16);
}
__device__ __forceinline__ float bflo(unsigned p) { union { unsigned u; float f; } c; c.u = p << 16; return c.f; }
__device__ __forceinline__ float bfhi(unsigned p) { union { unsigned u; float f; } c; c.u = p & 0xffff0000u; return c.f; }
__device__ __forceinline__ unsigned packbf(float a, float b) { return (unsigned)f2bf(a) | ((unsigned)f2bf(b) << 16); }

// ---------------- cnt zero (must precede bucket atomics; separate dispatch) ----------------
__global__ __launch_bounds__(256) void zero_kernel(int* __restrict__ cntpad) {
    int i = blockIdx.x * 256 + threadIdx.x;     // uint4 index
    if (i < NN * CSTRIDE / 4) ((uint4*)cntpad)[i] = make_uint4(0, 0, 0, 0);
}

// ---------------- merged prep + padded-slot CSR build (independent parts, one dispatch) ----
// R11 evidence: bucket (~40us) + prep (~25us) merged costs only ~45us (overlapped).
__global__ __launch_bounds__(256) void prepbucket_kernel(const int* __restrict__ src, const int* __restrict__ dst,
                                                         const float* __restrict__ x,
                                                         const float* __restrict__ W1l, const float* __restrict__ W1r,
                                                         const float* __restrict__ W2l, const float* __restrict__ W2r,
                                                         const float* __restrict__ W3l, const float* __restrict__ W3r,
                                                         int* __restrict__ cntpad, unsigned short* __restrict__ eidx,
                                                         unsigned short* __restrict__ xb,
                                                         unsigned short* __restrict__ Bw,
                                                         unsigned short* __restrict__ h1b,
                                                         unsigned short* __restrict__ h2b) {
    const int b = blockIdx.x;
    const int t = threadIdx.x;
    if (b < BKT_BLKS) {
        const int shard = b & (NSHARD - 1);
        const int chunk = b >> 3;
        const int lo = shard * SHARD_NODES;
        const int hi = lo + SHARD_NODES;
        int i = (chunk * 256 + t) * 4;
        if (i + 3 < EE) {
            int4 dv = *(const int4*)(dst + i);
            int4 sv = *(const int4*)(src + i);
            if (dv.x >= lo && dv.x < hi) { int p = atomicAdd(&cntpad[dv.x * CSTRIDE], 1); if (p < SLOTS) eidx[dv.x * SLOTS + p] = (unsigned short)sv.x; }
            if (dv.y >= lo && dv.y < hi) { int p = atomicAdd(&cntpad[dv.y * CSTRIDE], 1); if (p < SLOTS) eidx[dv.y * SLOTS + p] = (unsigned short)sv.y; }
            if (dv.z >= lo && dv.z < hi) { int p = atomicAdd(&cntpad[dv.z * CSTRIDE], 1); if (p < SLOTS) eidx[dv.z * SLOTS + p] = (unsigned short)sv.z; }
            if (dv.w >= lo && dv.w < hi) { int p = atomicAdd(&cntpad[dv.w * CSTRIDE], 1); if (p < SLOTS) eidx[dv.w * SLOTS + p] = (unsigned short)sv.w; }
        } else {
            for (int e = i; e < EE; ++e) {
                int d = dst[e];
                if (d >= lo && d < hi) {
                    int p = atomicAdd(&cntpad[d * CSTRIDE], 1);
                    if (p < SLOTS) eidx[d * SLOTS + p] = (unsigned short)src[e];
                }
            }
        }
    } else if (b < BKT_BLKS + CVT_BLKS) {
        int i = (b - BKT_BLKS) * 256 + t;         // float4 index, exactly NN*DD/4
        float4 v = ((const float4*)x)[i];
        uint2 o;
        o.x = packbf(v.x, v.y);
        o.y = packbf(v.z, v.w);
        ((uint2*)xb)[i] = o;
    } else if (b < BKT_BLKS + CVT_BLKS + WCAT_BLKS) {
        int gid = (b - BKT_BLKS - CVT_BLKS) * 256 + t;   // 0..98303
        int layer = gid >> 15;
        int rem = gid & 32767;
        int c = rem >> 8;
        int k = rem & 255;
        const float* Wl = (layer == 0) ? W1l : (layer == 1) ? W2l : W3l;
        const float* Wr = (layer == 0) ? W1r : (layer == 1) ? W2r : W3r;
        float v = (k < 128) ? Wl[(size_t)c * DD + k] : Wr[(size_t)c * DD + (k - 128)];
        Bw[gid] = f2bf(v);
    } else {
        // zero sentinel row NN of xb/h1b/h2b: 3 rows x 256B = 48 uint4
        if (t < 48) {
            unsigned short* base = (t < 16) ? xb : (t < 32) ? h1b : h2b;
            ((uint4*)(base + (size_t)NN * DD))[t & 15] = make_uint4(0, 0, 0, 0);
        }
    }
}

// ---------------- fused layer: gather 16 nodes -> LDS, then MFMA dual-GEMM ----------------
// R13 post-mortem: gather waves are memory-stalled (VALUBusy 30%, MfmaUtil 2%) with only
// 4 loads in flight per lane. Fix: process node PAIRS — issue both nodes' 8 loads before
// either reduction, overlapping node A's ~160cyc reduce chain with node B's load latency.
// 256-thread blocks (4 waves), 16-node tiles, 3125 blocks; (256,8) keeps VGPR<=64.
// GEMM: each wave computes the block's 16 rows x its 32-col strip (16 MFMA); A-frags from
// LDS, self rows from global. C/D: col=lane&15, row=(lane>>4)*4+reg (m89/m91-verified).
template <int RELU, int WRITE_F32>
__global__ __launch_bounds__(256, 8) void layer_kernel(const unsigned short* __restrict__ hb,
                                                       const unsigned short* __restrict__ eidx,
                                                       const int* __restrict__ cntpad,
                                                       const unsigned short* __restrict__ Bw,
                                                       const float* __restrict__ bias,
                                                       float* __restrict__ outf,
                                                       unsigned short* __restrict__ outb, int n) {
    __shared__ __align__(16) unsigned short sA[16][136];
    const int tid  = threadIdx.x;
    const int w    = tid >> 6;          // wave 0..3
    const int lane = tid & 63;
    const int row0 = blockIdx.x * 16;

    // ---- Phase A: gather 4 nodes per wave, processed as 2 interleaved pairs ----
    const int sub = lane >> 4;          // quarter 0..3
    const int q   = lane & 15;          // uint4 (16B) slot within the 256B row
#pragma unroll
    for (int jp = 0; jp < 2; ++jp) {
        // --- node pair: nA = row0 + w*4 + jp*2, nB = nA + 1 ---
        const int nA = row0 + w * 4 + jp * 2;
        const int nB = nA + 1;
        int degA = 0, capA = 0, degB = 0, capB = 0;
        int idxA = NN, idxB = NN;
        if (nA < n) {
            degA = cntpad[nA * CSTRIDE];
            capA = degA < SLOTS ? degA : SLOTS;
            idxA = eidx[nA * SLOTS + lane];
        }
        if (nB < n) {
            degB = cntpad[nB * CSTRIDE];
            capB = degB < SLOTS ? degB : SLOTS;
            idxB = eidx[nB * SLOTS + lane];
        }
        float A0 = 0.f, A1 = 0.f, A2 = 0.f, A3 = 0.f, A4 = 0.f, A5 = 0.f, A6 = 0.f, A7 = 0.f;
        float B0 = 0.f, B1 = 0.f, B2 = 0.f, B3 = 0.f, B4 = 0.f, B5 = 0.f, B6 = 0.f, B7 = 0.f;
        int capM = capA > capB ? capA : capB;
        for (int base = 0; base < capM; base += 16) {
            int t = base + sub;
            // issue all 8 loads (4 per node) before any reduction
            int a0i = __shfl(idxA, t);      a0i = (t      < capA) ? a0i : NN;
            int a1i = __shfl(idxA, t + 4);  a1i = (t + 4  < capA) ? a1i : NN;
            int a2i = __shfl(idxA, t + 8);  a2i = (t + 8  < capA) ? a2i : NN;
            int a3i = __shfl(idxA, t + 12); a3i = (t + 12 < capA) ? a3i : NN;
            int b0i = __shfl(idxB, t);      b0i = (t      < capB) ? b0i : NN;
            int b1i = __shfl(idxB, t + 4);  b1i = (t + 4  < capB) ? b1i : NN;
            int b2i = __shfl(idxB, t + 8);  b2i = (t + 8  < capB) ? b2i : NN;
            int b3i = __shfl(idxB, t + 12); b3i = (t + 12 < capB) ? b3i : NN;
            uint4 va0 = ((const uint4*)(hb + (size_t)a0i * DD))[q];
            uint4 va1 = ((const uint4*)(hb + (size_t)a1i * DD))[q];
            uint4 va2 = ((const uint4*)(hb + (size_t)a2i * DD))[q];
            uint4 va3 = ((const uint4*)(hb + (size_t)a3i * DD))[q];
            uint4 vb0 = ((const uint4*)(hb + (size_t)b0i * DD))[q];
            uint4 vb1 = ((const uint4*)(hb + (size_t)b1i * DD))[q];
            uint4 vb2 = ((const uint4*)(hb + (size_t)b2i * DD))[q];
            uint4 vb3 = ((const uint4*)(hb + (size_t)b3i * DD))[q];
            A0 += (bflo(va0.x) + bflo(va1.x)) + (bflo(va2.x) + bflo(va3.x));
            A1 += (bfhi(va0.x) + bfhi(va1.x)) + (bfhi(va2.x) + bfhi(va3.x));
            A2 += (bflo(va0.y) + bflo(va1.y)) + (bflo(va2.y) + bflo(va3.y));
            A3 += (bfhi(va0.y) + bfhi(va1.y)) + (bfhi(va2.y) + bfhi(va3.y));
            A4 += (bflo(va0.z) + bflo(va1.z)) + (bflo(va2.z) + bflo(va3.z));
            A5 += (bfhi(va0.z) + bfhi(va1.z)) + (bfhi(va2.z) + bfhi(va3.z));
            A6 += (bflo(va0.w) + bflo(va1.w)) + (bflo(va2.w) + bflo(va3.w));
            A7 += (bfhi(va0.w) + bfhi(va1.w)) + (bfhi(va2.w) + bfhi(va3.w));
            B0 += (bflo(vb0.x) + bflo(vb1.x)) + (bflo(vb2.x) + bflo(vb3.x));
            B1 += (bfhi(vb0.x) + bfhi(vb1.x)) + (bfhi(vb2.x) + bfhi(vb3.x));
            B2 += (bflo(vb0.y) + bflo(vb1.y)) + (bflo(vb2.y) + bflo(vb3.y));
            B3 += (bfhi(vb0.y) + bfhi(vb1.y)) + (bfhi(vb2.y) + bfhi(vb3.y));
            B4 += (bflo(vb0.z) + bflo(vb1.z)) + (bflo(vb2.z) + bflo(vb3.z));
            B5 += (bfhi(vb0.z) + bfhi(vb1.z)) + (bfhi(vb2.z) + bfhi(vb3.z));
            B6 += (bflo(vb0.w) + bflo(vb1.w)) + (bflo(vb2.w) + bflo(vb3.w));
            B7 += (bfhi(vb0.w) + bfhi(vb1.w)) + (bfhi(vb2.w) + bfhi(vb3.w));
        }
        // interleaved butterfly reductions (independent chains)
        A0 += __shfl_xor(A0, 16); B0 += __shfl_xor(B0, 16);
        A1 += __shfl_xor(A1, 16); B1 += __shfl_xor(B1, 16);
        A2 += __shfl_xor(A2, 16); B2 += __shfl_xor(B2, 16);
        A3 += __shfl_xor(A3, 16); B3 += __shfl_xor(B3, 16);
        A4 += __shfl_xor(A4, 16); B4 += __shfl_xor(B4, 16);
        A5 += __shfl_xor(A5, 16); B5 += __shfl_xor(B5, 16);
        A6 += __shfl_xor(A6, 16); B6 += __shfl_xor(B6, 16);
        A7 += __shfl_xor(A7, 16); B7 += __shfl_xor(B7, 16);
        A0 += __shfl_xor(A0, 32); B0 += __shfl_xor(B0, 32);
        A1 += __shfl_xor(A1, 32); B1 += __shfl_xor(B1, 32);
        A2 += __shfl_xor(A2, 32); B2 += __shfl_xor(B2, 32);
        A3 += __shfl_xor(A3, 32); B3 += __shfl_xor(B3, 32);
        A4 += __shfl_xor(A4, 32); B4 += __shfl_xor(B4, 32);
        A5 += __shfl_xor(A5, 32); B5 += __shfl_xor(B5, 32);
        A6 += __shfl_xor(A6, 32); B6 += __shfl_xor(B6, 32);
        A7 += __shfl_xor(A7, 32); B7 += __shfl_xor(B7, 32);
        if (sub == 0) {
            float invA = (degA > 0) ? (1.0f / (float)degA) : 0.f;
            uint4 oA;
            oA.x = packbf(A0 * invA, A1 * invA);
            oA.y = packbf(A2 * invA, A3 * invA);
            oA.z = packbf(A4 * invA, A5 * invA);
            oA.w = packbf(A6 * invA, A7 * invA);
            *(uint4*)&sA[w * 4 + jp * 2][q * 8] = oA;
            float invB = (degB > 0) ? (1.0f / (float)degB) : 0.f;
            uint4 oB;
            oB.x = packbf(B0 * invB, B1 * invB);
            oB.y = packbf(B2 * invB, B3 * invB);
            oB.z = packbf(B4 * invB, B5 * invB);
            oB.w = packbf(B6 * invB, B7 * invB);
            *(uint4*)&sA[w * 4 + jp * 2 + 1][q * 8] = oB;
        }
    }
    __syncthreads();

    // ---- Phase B: MFMA dual-GEMM. All waves share the 16 rows; wave w owns 32 cols ----
    const int m    = lane & 15;
    const int quad = lane >> 4;
    const int arow = row0 + m;
    const bool rv  = (arow < n);

    f32x4 acc[2];
    acc[0] = (f32x4){0.f, 0.f, 0.f, 0.f};
    acc[1] = (f32x4){0.f, 0.f, 0.f, 0.f};

    const unsigned short* aptr = hb + (size_t)arow * DD + quad * 8;
#pragma unroll
    for (int ph = 0; ph < 2; ++ph) {
#pragma unroll
        for (int ks = 0; ks < 4; ++ks) {
            bf16x8 af;
            if (ph == 0) {
                af = *(const bf16x8*)&sA[m][ks * 32 + quad * 8];
            } else {
                af = (bf16x8){0, 0, 0, 0, 0, 0, 0, 0};
                if (rv) af = *(const bf16x8*)(aptr + ks * 32);
            }
            const int koff = ph * 128 + ks * 32 + quad * 8;
#pragma unroll
            for (int ct = 0; ct < 2; ++ct) {
                const int c = w * 32 + ct * 16 + m;
                bf16x8 bfv = *(const bf16x8*)(Bw + (size_t)c * 256 + koff);
                acc[ct] = __builtin_amdgcn_mfma_f32_16x16x32_bf16(af, bfv, acc[ct], 0, 0, 0);
            }
        }
    }

#pragma unroll
    for (int ct = 0; ct < 2; ++ct) {
        const int gcol = w * 32 + ct * 16 + m;
        const float bv = bias[gcol];
#pragma unroll
        for (int r = 0; r < 4; ++r) {
            const int grow = row0 + quad * 4 + r;
            if (grow < n) {
                float v = acc[ct][r] + bv;
                if (RELU) v = fmaxf(v, 0.f);
                if (WRITE_F32) outf[(size_t)grow * DD + gcol] = v;
                else           outb[(size_t)grow * DD + gcol] = f2bf(v);
            }
        }
    }
}

extern "C" void kernel_launch(void* const* d_in, const int* in_sizes, int n_in,
                              void* d_out, int out_size, void* d_ws, size_t ws_size,
                              hipStream_t stream) {
    const float* x    = (const float*)d_in[0];
    const int*   edge = (const int*)d_in[1];     // [2, E] int32
    const int*   srcp = edge;
    const int*   dstp = edge + EE;
    const float* W1l = (const float*)d_in[2];
    const float* b1  = (const float*)d_in[3];
    const float* W1r = (const float*)d_in[4];
    const float* W2l = (const float*)d_in[5];
    const float* b2  = (const float*)d_in[6];
    const float* W2r = (const float*)d_in[7];
    const float* W3l = (const float*)d_in[8];
    const float* b3  = (const float*)d_in[9];
    const float* W3r = (const float*)d_in[10];
    float* out = (float*)d_out;

    char* ws = (char*)d_ws;
    size_t off = 0;
    auto alloc = [&](size_t bytes) { void* p = ws + off; off += (bytes + 255) & ~(size_t)255; return p; };
    unsigned short* eidx   = (unsigned short*)alloc((size_t)NN * SLOTS * 2);      // 6.4 MB padded slots
    int*            cntpad = (int*)           alloc((size_t)NN * CSTRIDE * 4);    // 3.2 MB line-strided counters
    unsigned short* Bw     = (unsigned short*)alloc((size_t)3 * DD * 256 * 2);
    unsigned short* xb     = (unsigned short*)alloc((size_t)(NN + 1) * DD * 2);   // +1 zero row (sentinel NN)
    unsigned short* h1b    = (unsigned short*)alloc((size_t)(NN + 1) * DD * 2);
    unsigned short* h2b    = (unsigned short*)alloc((size_t)(NN + 1) * DD * 2);

    zero_kernel<<<(NN * CSTRIDE / 4 + 255) / 256, 256, 0, stream>>>(cntpad);

    const int pb_grid = BKT_BLKS + CVT_BLKS + WCAT_BLKS + ZR_BLKS;
    prepbucket_kernel<<<pb_grid, 256, 0, stream>>>(srcp, dstp, x, W1l, W1r, W2l, W2r, W3l, W3r,
                                                   cntpad, eidx, xb, Bw, h1b, h2b);

    const int layer_grid = (NN + 15) / 16;     // 3125

    // layer 1: xb -> h1b (ReLU)
    layer_kernel<1, 0><<<layer_grid, 256, 0, stream>>>(xb, eidx, cntpad, Bw, b1, nullptr, h1b, NN);
    // layer 2: h1b -> h2b (ReLU)
    layer_kernel<1, 0><<<layer_grid, 256, 0, stream>>>(h1b, eidx, cntpad, Bw + 32768, b2, nullptr, h2b, NN);
    // layer 3: h2b -> out fp32 (no ReLU)
    layer_kernel<0, 1><<<layer_grid, 256, 0, stream>>>(h2b, eidx, cntpad, Bw + 65536, b3, out, nullptr, NN);
}